// Round 3
// baseline (100.846 us; speedup 1.0000x reference)
//
#include <hip/hip_runtime.h>

// SmoothnessLoss: smooth[i] = sum_{j<64} |x[i+j] - mean_j(x[i+j])| for both inputs,
// out = mean((smoothHat - smoothY)^2) over W = N-k-1 windows. k fixed at 64.
//
// R3: same C=4 register-blocked structure as R2, but:
//  - arrays processed in a NON-unrolled loop reusing ONE e[68] register buffer
//    (R2 inlined both calls -> two live 68-float arrays, ~150 VGPR, spill risk)
//  - all 64-length float accumulation chains split into 4 independent partials
//    (strict-fp serial chains at ~4cyc dep latency were a latency bound at
//     ~3.8 waves/SIMD; reassociation is fine vs 0.925 absmax threshold)

#define K     64
#define C     4                 // windows per thread
#define BLK   256
#define WPB   (BLK * C)         // 1024 windows per block
#define TILE  (WPB + K)         // 1088 floats staged per array
#define TILE4 (TILE / 4)        // 272 float4

__global__ __launch_bounds__(BLK) void smoothness_loss_kernel(
    const float* __restrict__ yHat, const float* __restrict__ y,
    float* __restrict__ out, int N, int W, float invW)
{
    __shared__ __align__(16) float sA[TILE];   // 4.25 KB
    __shared__ __align__(16) float sB[TILE];
    __shared__ float wave_sums[BLK / 64];

    const int base = blockIdx.x * WPB;         // multiple of 1024 -> float4-aligned
    const int tid  = threadIdx.x;

    // Stage 272 float4 per array with 256 threads (2 rounds, 2nd partial).
    // N % 4 == 0, so a float4 is either fully in-bounds or fully out.
    const float4* gA = (const float4*)(yHat + base);
    const float4* gB = (const float4*)(y + base);
    const int g4max = (N - base) / 4;
    #pragma unroll
    for (int r = 0; r < 2; ++r) {
        const int i4 = tid + r * BLK;
        if (i4 < TILE4) {
            float4 a = make_float4(0.f, 0.f, 0.f, 0.f), b = a;
            if (i4 < g4max) { a = gA[i4]; b = gB[i4]; }
            ((float4*)sA)[i4] = a;
            ((float4*)sB)[i4] = b;
        }
    }
    __syncthreads();

    const int o  = tid * C;        // local float offset, multiple of 4 -> 16B-aligned
    const int w0 = base + o;

    float dAll[2][C];

    #pragma unroll 1               // do NOT unroll: reuse one e[] buffer for both arrays
    for (int arr = 0; arr < 2; ++arr) {
        const float* s = (arr == 0) ? sA : sB;

        float e[K + C];            // 68 floats, all indices constant after unroll
        const float4* p = (const float4*)(s + o);
        #pragma unroll
        for (int i = 0; i < (K + C) / 4; ++i) {
            float4 t = p[i];
            e[4 * i + 0] = t.x; e[4 * i + 1] = t.y;
            e[4 * i + 2] = t.z; e[4 * i + 3] = t.w;
        }

        // window-0 sum: 4 independent partials (16-deep chains instead of 64)
        float a0 = 0.f, a1 = 0.f, a2 = 0.f, a3 = 0.f;
        #pragma unroll
        for (int j = 0; j < K; j += 4) {
            a0 += e[j + 0]; a1 += e[j + 1]; a2 += e[j + 2]; a3 += e[j + 3];
        }
        float sums[C];
        sums[0] = (a0 + a1) + (a2 + a3);
        #pragma unroll
        for (int c = 1; c < C; ++c)
            sums[c] = sums[c - 1] + (e[K + c - 1] - e[c - 1]);

        // abs-dev per window: 4 independent partials each
        #pragma unroll
        for (int c = 0; c < C; ++c) {
            const float m = sums[c] * (1.0f / K);
            float d0 = 0.f, d1 = 0.f, d2 = 0.f, d3 = 0.f;
            #pragma unroll
            for (int j = 0; j < K; j += 4) {
                d0 += fabsf(e[c + j + 0] - m);
                d1 += fabsf(e[c + j + 1] - m);
                d2 += fabsf(e[c + j + 2] - m);
                d3 += fabsf(e[c + j + 3] - m);
            }
            dAll[arr][c] = (d0 + d1) + (d2 + d3);
        }
    }

    float part = 0.f;
    #pragma unroll
    for (int c = 0; c < C; ++c) {
        if (w0 + c < W) {
            const float diff = dAll[0][c] - dAll[1][c];
            part += diff * diff;
        }
    }

    // wave-64 shuffle reduction -> per-wave LDS -> one atomic per block
    #pragma unroll
    for (int off = 32; off > 0; off >>= 1)
        part += __shfl_down(part, off, 64);

    const int lane = tid & 63;
    const int wv   = tid >> 6;
    if (lane == 0) wave_sums[wv] = part;
    __syncthreads();

    if (tid == 0) {
        float s = 0.f;
        #pragma unroll
        for (int i = 0; i < BLK / 64; ++i) s += wave_sums[i];
        atomicAdd(out, s * invW);
    }
}

extern "C" void kernel_launch(void* const* d_in, const int* in_sizes, int n_in,
                              void* d_out, int out_size, void* d_ws, size_t ws_size,
                              hipStream_t stream) {
    const float* yHat = (const float*)d_in[0];
    const float* y    = (const float*)d_in[1];
    float* out        = (float*)d_out;

    const int N = in_sizes[0];     // 1,000,000
    const int W = N - K - 1;       // 999,935
    const float invW = 1.0f / (float)W;

    hipMemsetAsync(out, 0, sizeof(float), stream);  // d_out re-poisoned each call

    const int grid = (W + WPB - 1) / WPB;           // 977 blocks
    smoothness_loss_kernel<<<grid, BLK, 0, stream>>>(yHat, y, out, N, W, invW);
}

// Round 4
// 76.398 us; speedup vs baseline: 1.3200x; 1.3200x over previous
//
#include <hip/hip_runtime.h>

// SmoothnessLoss: smooth[i] = sum_{j<64} |x[i+j] - mean_j(x[i+j])| for both inputs,
// out = mean((smoothHat - smoothY)^2) over W = N-k-1 windows. k fixed at 64.
//
// R4 = R2 structure + ILP chain-split.
// HARD-WON (R3): the e[68] register promotion only happens with a COMPILE-TIME
// LDS base and full inlining/unrolling. A runtime-selected `s` pointer inside a
// #pragma unroll 1 loop demoted e[] to per-use ds_read_b32 (VGPR 72, 3.2e6 bank
// conflicts from the stride-4 lane layout, 2x slower). Keep the two calls
// inlined as templates over the array; accept ~150 VGPR.
// Chain-split: all 64-long fp add chains -> 4 independent partials (dep 64->16,
// ~4cyc dep latency was the bound at ~15 waves/CU; reassoc fine vs 0.925 thr).

#define K     64
#define C     4                 // windows per thread
#define BLK   256
#define WPB   (BLK * C)         // 1024 windows per block
#define TILE  (WPB + K)         // 1088 floats staged per array
#define TILE4 (TILE / 4)        // 272 float4

__device__ __forceinline__ void windows_saod(const float* s /* compile-time base! */,
                                             int o, float outd[C]) {
    float e[K + C];             // 68 floats -> VGPRs (constant indices, full unroll)
    const float4* p = (const float4*)(s + o);   // o = 4*tid -> 16B-aligned, b128
    #pragma unroll
    for (int i = 0; i < (K + C) / 4; ++i) {
        float4 t = p[i];
        e[4 * i + 0] = t.x; e[4 * i + 1] = t.y;
        e[4 * i + 2] = t.z; e[4 * i + 3] = t.w;
    }
    // window-0 sum: 4 independent partials
    float a0 = 0.f, a1 = 0.f, a2 = 0.f, a3 = 0.f;
    #pragma unroll
    for (int j = 0; j < K; j += 4) {
        a0 += e[j + 0]; a1 += e[j + 1]; a2 += e[j + 2]; a3 += e[j + 3];
    }
    float sums[C];
    sums[0] = (a0 + a1) + (a2 + a3);
    #pragma unroll
    for (int c = 1; c < C; ++c)
        sums[c] = sums[c - 1] + (e[K + c - 1] - e[c - 1]);

    // abs-dev per window: 4 independent partials each
    #pragma unroll
    for (int c = 0; c < C; ++c) {
        const float m = sums[c] * (1.0f / K);
        float d0 = 0.f, d1 = 0.f, d2 = 0.f, d3 = 0.f;
        #pragma unroll
        for (int j = 0; j < K; j += 4) {
            d0 += fabsf(e[c + j + 0] - m);
            d1 += fabsf(e[c + j + 1] - m);
            d2 += fabsf(e[c + j + 2] - m);
            d3 += fabsf(e[c + j + 3] - m);
        }
        outd[c] = (d0 + d1) + (d2 + d3);
    }
}

__global__ __launch_bounds__(BLK) void smoothness_loss_kernel(
    const float* __restrict__ yHat, const float* __restrict__ y,
    float* __restrict__ out, int N, int W, float invW)
{
    __shared__ __align__(16) float sA[TILE];   // 4.25 KB
    __shared__ __align__(16) float sB[TILE];
    __shared__ float wave_sums[BLK / 64];

    const int base = blockIdx.x * WPB;         // multiple of 1024 -> float4-aligned
    const int tid  = threadIdx.x;

    // Stage 272 float4 per array with 256 threads (2 rounds, 2nd partial).
    // N % 4 == 0, so a float4 is either fully in-bounds or fully out.
    const float4* gA = (const float4*)(yHat + base);
    const float4* gB = (const float4*)(y + base);
    const int g4max = (N - base) / 4;
    #pragma unroll
    for (int r = 0; r < 2; ++r) {
        const int i4 = tid + r * BLK;
        if (i4 < TILE4) {
            float4 a = make_float4(0.f, 0.f, 0.f, 0.f), b = a;
            if (i4 < g4max) { a = gA[i4]; b = gB[i4]; }
            ((float4*)sA)[i4] = a;
            ((float4*)sB)[i4] = b;
        }
    }
    __syncthreads();

    const int o  = tid * C;        // local float offset, multiple of 4 -> 16B-aligned
    const int w0 = base + o;

    float dA[C], dB[C];
    windows_saod(sA, o, dA);       // both fully inlined; compiler serializes,
    windows_saod(sB, o, dB);       // peak live ~150 VGPR (verified OK in R2)

    float part = 0.f;
    #pragma unroll
    for (int c = 0; c < C; ++c) {
        if (w0 + c < W) {
            const float diff = dA[c] - dB[c];
            part += diff * diff;
        }
    }

    // wave-64 shuffle reduction -> per-wave LDS -> one atomic per block
    #pragma unroll
    for (int off = 32; off > 0; off >>= 1)
        part += __shfl_down(part, off, 64);

    const int lane = tid & 63;
    const int wv   = tid >> 6;
    if (lane == 0) wave_sums[wv] = part;
    __syncthreads();

    if (tid == 0) {
        float s = 0.f;
        #pragma unroll
        for (int i = 0; i < BLK / 64; ++i) s += wave_sums[i];
        atomicAdd(out, s * invW);
    }
}

extern "C" void kernel_launch(void* const* d_in, const int* in_sizes, int n_in,
                              void* d_out, int out_size, void* d_ws, size_t ws_size,
                              hipStream_t stream) {
    const float* yHat = (const float*)d_in[0];
    const float* y    = (const float*)d_in[1];
    float* out        = (float*)d_out;

    const int N = in_sizes[0];     // 1,000,000
    const int W = N - K - 1;       // 999,935
    const float invW = 1.0f / (float)W;

    hipMemsetAsync(out, 0, sizeof(float), stream);  // d_out re-poisoned each call

    const int grid = (W + WPB - 1) / WPB;           // 977 blocks
    smoothness_loss_kernel<<<grid, BLK, 0, stream>>>(yHat, y, out, N, W, invW);
}